// Round 8
// baseline (722.067 us; speedup 1.0000x reference)
//
#include <hip/hip_runtime.h>
#include <math.h>

typedef float f32x4 __attribute__((ext_vector_type(4)));
typedef __bf16 bf16x8 __attribute__((ext_vector_type(8)));
typedef unsigned short u16x8 __attribute__((ext_vector_type(8)));
typedef unsigned short u16x4 __attribute__((ext_vector_type(4)));

#define LN2F_ 0.69314718055994530942f

__device__ inline unsigned short f2bf(float f) {
    unsigned u = __builtin_bit_cast(unsigned, f);
    u += 0x7fffu + ((u >> 16) & 1u);
    return (unsigned short)(u >> 16);
}

// ---------------------------------------------------------------------------
// fp32 -> bf16 bulk convert (V: tiny; X: 134 MB -> 67 MB, ~33 us streaming)
// ---------------------------------------------------------------------------
__global__ __launch_bounds__(256) void k_cvt(const float* __restrict__ in,
                                             unsigned short* __restrict__ out, int n4) {
    int i = blockIdx.x * 256 + threadIdx.x;
    if (i >= n4) return;
    float4 v = ((const float4*)in)[i];
    u16x4 o = { f2bf(v.x), f2bf(v.y), f2bf(v.z), f2bf(v.w) };
    *(u16x4*)(out + (size_t)i * 4) = o;
}

// am[h][p][j] = bf16(alpha[h][(j - p) & 1023])
__global__ __launch_bounds__(256) void k_build_am(const float* __restrict__ alpha,
                                                  unsigned short* __restrict__ am) {
    int t = blockIdx.x * 256 + threadIdx.x;          // 0 .. 1048575
    int j8 = (t & 127) << 3;
    int p  = (t >> 7) & 1023;
    int h  = t >> 17;
    const float* ar = alpha + (h << 10);
    u16x8 o;
#pragma unroll
    for (int q = 0; q < 8; ++q) o[q] = f2bf(ar[(j8 + q - p) & 1023]);
    *(u16x8*)(am + ((size_t)t << 3)) = o;
}

// WT[e'][e] = bf16(W[e][e'])
__global__ __launch_bounds__(256) void k_build_wt(const float* __restrict__ W,
                                                  unsigned short* __restrict__ WT) {
    int t = blockIdx.x * 256 + threadIdx.x;          // 0 .. 262143
    int e1 = t >> 9, e = t & 511;
    WT[t] = f2bf(W[e * 512 + e1]);
}

// ---------------------------------------------------------------------------
// Direct-to-register MFMA GEMMs (r8): NO LDS, NO barriers.
//   16x16x32 A/B fragment = lane(ml,quad) <- row ml, k = quad*8..+7 (16B,
//   row-major contiguous) -> load fragments straight from global.
//   r7 post-mortem: MfmaUtil pinned at ~24% across 3 different global->LDS
//   schedules; binding resource was the LDS read/write port (8 ds_read_b128
//   + staging per 16 MFMA) + barrier lockstep, not the HBM pipeline.
//   Per-block per-step working set ~16 KB -> L1 serves the 2x/4x intra-block
//   fragment redundancy; co-XCD L2 remaps (verified r3) catch cross-block.
//   Latency hiding: register double-buffer (static names, rule #20) + free-
//   running waves (no barriers) + setprio(1) around MFMA clusters (T5).
// ---------------------------------------------------------------------------

// ---------------------------------------------------------------------------
// K1: wsT[n][e][p] = sum_d Xb[(n,p)][d] * Vb[e][d]   (A,B bf16 row-major K=512)
//   4 waves x (64x64 tile); XCD remap: 4 e-blocks per X panel co-XCD.
// ---------------------------------------------------------------------------
__global__ __launch_bounds__(256) void k_gemm1(const unsigned short* __restrict__ A,
                                               const unsigned short* __restrict__ B,
                                               unsigned short* __restrict__ wsT) {
    const int tid = threadIdx.x;
    const int flat = blockIdx.x;
    const int xcd = flat & 7, slot = flat >> 3;
    const int m0 = (xcd * 64 + (slot >> 2)) * 128;
    const int e0 = (slot & 3) * 128;
    const int w = tid >> 6, lane = tid & 63, ml = lane & 15, quad = lane >> 4;
    const int wr = w >> 1, wc = w & 1;
    const unsigned short* pa = A + (size_t)(m0 + wr * 64 + ml) * 512 + quad * 8;
    const unsigned short* pb = B + (size_t)(e0 + wc * 64 + ml) * 512 + quad * 8;
    f32x4 acc[4][4] = {};
    u16x8 aE[4], bE[4], aO[4], bO[4];
    auto LOAD = [&](u16x8* ar, u16x8* br, int ko) {
#pragma unroll
        for (int i = 0; i < 4; ++i) {
            ar[i] = *(const u16x8*)(pa + (size_t)i * 8192 + ko);   // row stride 16*512
            br[i] = *(const u16x8*)(pb + (size_t)i * 8192 + ko);
        }
    };
    auto MF = [&](u16x8* ar, u16x8* br) {
        __builtin_amdgcn_s_setprio(1);
#pragma unroll
        for (int i = 0; i < 4; ++i)
#pragma unroll
            for (int j = 0; j < 4; ++j)
                acc[i][j] = __builtin_amdgcn_mfma_f32_16x16x32_bf16(
                    __builtin_bit_cast(bf16x8, ar[i]),
                    __builtin_bit_cast(bf16x8, br[j]), acc[i][j], 0, 0, 0);
        __builtin_amdgcn_s_setprio(0);
    };
    LOAD(aE, bE, 0);
    for (int k0 = 0; k0 < 512; k0 += 64) {
        if (k0 + 32 < 512) LOAD(aO, bO, k0 + 32);
        MF(aE, bE);
        if (k0 + 64 < 512) LOAD(aE, bE, k0 + 64);
        MF(aO, bO);
    }
    const int n = m0 >> 10;
    const int pblk = m0 & 1023;
#pragma unroll
    for (int i = 0; i < 4; ++i) {
        int p = pblk + wr * 64 + i * 16 + quad * 4;
#pragma unroll
        for (int j = 0; j < 4; ++j) {
            int e = e0 + wc * 64 + j * 16 + ml;
            u16x4 o = { f2bf(acc[i][j][0]), f2bf(acc[i][j][1]),
                        f2bf(acc[i][j][2]), f2bf(acc[i][j][3]) };
            *(u16x4*)(wsT + ((size_t)n * 512 + e) * 1024 + p) = o;
        }
    }
}

// ---------------------------------------------------------------------------
// K2: y[n][p][h*64+r] = sum_j am[h][p][j] * wsT[n][h*64+r][j]   (K=1024)
//   n-batched 4; 512 threads = 8 waves = (4 n) x (2 p-halves), 64x64 tiles.
//   XCD remap: 8 p-blocks per wsT A-panel co-XCD (kept from round 3).
// ---------------------------------------------------------------------------
__global__ __launch_bounds__(512) void k_gemm2(const unsigned short* __restrict__ wsT,
                                               const unsigned short* __restrict__ am,
                                               unsigned short* __restrict__ y) {
    const int tid = threadIdx.x;
    const int flat = blockIdx.x;
    const int xcd = flat & 7, slot = flat >> 3;
    const int panel = xcd * 16 + (slot >> 3);
    const int p0 = (slot & 7) * 128;
    const int h  = panel & 7;
    const int n0 = (panel >> 3) * 4;
    const int w = tid >> 6, lane = tid & 63, ml = lane & 15, quad = lane >> 4;
    const int wn = w >> 1, wp = w & 1;
    const unsigned short* pa = wsT + (size_t)(n0 + wn) * 524288
                                   + (size_t)(h * 64 + ml) * 1024 + quad * 8;
    const unsigned short* pb = am + ((size_t)h * 1024 + p0 + wp * 64 + ml) * 1024 + quad * 8;
    f32x4 acc[4][4] = {};
    u16x8 aE[4], bE[4], aO[4], bO[4];
    auto LOAD = [&](u16x8* ar, u16x8* br, int ko) {
#pragma unroll
        for (int i = 0; i < 4; ++i) {
            ar[i] = *(const u16x8*)(pa + (size_t)i * 16384 + ko);  // row stride 16*1024
            br[i] = *(const u16x8*)(pb + (size_t)i * 16384 + ko);
        }
    };
    auto MF = [&](u16x8* ar, u16x8* br) {
        __builtin_amdgcn_s_setprio(1);
#pragma unroll
        for (int mt = 0; mt < 4; ++mt)
#pragma unroll
            for (int nt = 0; nt < 4; ++nt)
                acc[mt][nt] = __builtin_amdgcn_mfma_f32_16x16x32_bf16(
                    __builtin_bit_cast(bf16x8, ar[mt]),
                    __builtin_bit_cast(bf16x8, br[nt]), acc[mt][nt], 0, 0, 0);
        __builtin_amdgcn_s_setprio(0);
    };
    LOAD(aE, bE, 0);
    for (int k0 = 0; k0 < 1024; k0 += 64) {
        if (k0 + 32 < 1024) LOAD(aO, bO, k0 + 32);
        MF(aE, bE);
        if (k0 + 64 < 1024) LOAD(aE, bE, k0 + 64);
        MF(aO, bO);
    }
    const int n = n0 + wn;
#pragma unroll
    for (int mt = 0; mt < 4; ++mt) {
        int r0 = mt * 16 + quad * 4;
#pragma unroll
        for (int nt = 0; nt < 4; ++nt) {
            int p = p0 + wp * 64 + nt * 16 + ml;
            u16x4 o = { f2bf(acc[mt][nt][0]), f2bf(acc[mt][nt][1]),
                        f2bf(acc[mt][nt][2]), f2bf(acc[mt][nt][3]) };
            *(u16x4*)(y + ((size_t)n * 1024 + p) * 512 + h * 64 + r0) = o;
        }
    }
}

// ---------------------------------------------------------------------------
// K3: out[m][e'] = log_cosh( sum_e y[m][e] * WT[e'][e] + b[e'] )  (fp32 out)
//   Same direct-reg structure as K1; logcosh epilogue via __expf/__logf.
// ---------------------------------------------------------------------------
__global__ __launch_bounds__(256) void k_gemm3(const unsigned short* __restrict__ A,
                                               const unsigned short* __restrict__ B,
                                               const float* __restrict__ bias,
                                               float* __restrict__ out) {
    const int tid = threadIdx.x;
    const int flat = blockIdx.x;
    const int xcd = flat & 7, slot = flat >> 3;
    const int m0 = (xcd * 64 + (slot >> 2)) * 128;
    const int e0 = (slot & 3) * 128;
    const int w = tid >> 6, lane = tid & 63, ml = lane & 15, quad = lane >> 4;
    const int wr = w >> 1, wc = w & 1;
    const unsigned short* pa = A + (size_t)(m0 + wr * 64 + ml) * 512 + quad * 8;
    const unsigned short* pb = B + (size_t)(e0 + wc * 64 + ml) * 512 + quad * 8;
    f32x4 acc[4][4] = {};
    u16x8 aE[4], bE[4], aO[4], bO[4];
    auto LOAD = [&](u16x8* ar, u16x8* br, int ko) {
#pragma unroll
        for (int i = 0; i < 4; ++i) {
            ar[i] = *(const u16x8*)(pa + (size_t)i * 8192 + ko);
            br[i] = *(const u16x8*)(pb + (size_t)i * 8192 + ko);
        }
    };
    auto MF = [&](u16x8* ar, u16x8* br) {
        __builtin_amdgcn_s_setprio(1);
#pragma unroll
        for (int i = 0; i < 4; ++i)
#pragma unroll
            for (int j = 0; j < 4; ++j)
                acc[i][j] = __builtin_amdgcn_mfma_f32_16x16x32_bf16(
                    __builtin_bit_cast(bf16x8, ar[i]),
                    __builtin_bit_cast(bf16x8, br[j]), acc[i][j], 0, 0, 0);
        __builtin_amdgcn_s_setprio(0);
    };
    LOAD(aE, bE, 0);
    for (int k0 = 0; k0 < 512; k0 += 64) {
        if (k0 + 32 < 512) LOAD(aO, bO, k0 + 32);
        MF(aE, bE);
        if (k0 + 64 < 512) LOAD(aE, bE, k0 + 64);
        MF(aO, bO);
    }
#pragma unroll
    for (int j = 0; j < 4; ++j) {
        int e = e0 + wc * 64 + j * 16 + ml;
        float bv = bias[e];
#pragma unroll
        for (int i = 0; i < 4; ++i) {
            int mg = m0 + wr * 64 + i * 16 + quad * 4;
#pragma unroll
            for (int r = 0; r < 4; ++r) {
                float v  = acc[i][j][r] + bv;
                float ax = fabsf(v);
                float t  = __expf(-2.0f * ax);
                out[(size_t)(mg + r) * 512 + e] = ax + __logf(1.0f + t) - LN2F_;
            }
        }
    }
}

// ---------------------------------------------------------------------------
// Buffers:
//   d_out (134 MB): [am 16.8 MB | Vb 0.5 MB | Xb 67 MB]  (all consumed before
//                    K3 writes `out` over the region)
//   d_ws  (134 MB): [wsT 67 MB (reused for WT after K2) | y 67 MB]
// Order: cvt(V), cvt(X), build_am -> K1 -> K2 -> build_wt -> K3
// ---------------------------------------------------------------------------
extern "C" void kernel_launch(void* const* d_in, const int* in_sizes, int n_in,
                              void* d_out, int out_size, void* d_ws, size_t ws_size,
                              hipStream_t stream) {
    const float* x     = (const float*)d_in[0];
    const float* alpha = (const float*)d_in[1];
    const float* V     = (const float*)d_in[2];
    const float* W     = (const float*)d_in[3];
    const float* b     = (const float*)d_in[4];

    unsigned short* am  = (unsigned short*)d_out;
    unsigned short* Vb  = am + 8388608;
    unsigned short* Xb  = Vb + 262144;
    unsigned short* wsT = (unsigned short*)d_ws;
    unsigned short* y   = wsT + 33554432;
    unsigned short* WT  = wsT;
    float* out = (float*)d_out;

    k_cvt<<<256, 256, 0, stream>>>(V, Vb, 65536);
    k_cvt<<<32768, 256, 0, stream>>>(x, Xb, 8388608);
    k_build_am<<<4096, 256, 0, stream>>>(alpha, am);

    k_gemm1<<<dim3(2048), 256, 0, stream>>>(Xb, Vb, wsT);
    k_gemm2<<<dim3(1024), 512, 0, stream>>>(wsT, am, y);
    k_build_wt<<<1024, 256, 0, stream>>>(W, WT);
    k_gemm3<<<dim3(2048), 256, 0, stream>>>(y, WT, b, out);
}